// Round 8
// baseline (72.348 us; speedup 1.0000x reference)
//
#include <hip/hip_runtime.h>
#include <hip/hip_fp16.h>
#include <math.h>

typedef __attribute__((ext_vector_type(8))) _Float16 f16x8;
typedef __attribute__((ext_vector_type(4))) float f32x4;

#define TBL 512
#define UMAXV (1.0f/11.0f)

// swizzled 16B-quad element index within a [rows][64-f16] LDS tile
__device__ __forceinline__ int swq(int row, int q) {
  return row * 64 + ((q ^ (row & 7)) << 3);
}
__device__ __forceinline__ f16x8 cvt8(float4 a, float4 b) {
  f16x8 r;
  r[0] = (_Float16)a.x; r[1] = (_Float16)a.y;
  r[2] = (_Float16)a.z; r[3] = (_Float16)a.w;
  r[4] = (_Float16)b.x; r[5] = (_Float16)b.y;
  r[6] = (_Float16)b.z; r[7] = (_Float16)b.w;
  return r;
}

// ---------------- K_prep: transpose+cvt Wqkv/Wout to fp16; build tables -----
__global__ __launch_bounds__(256) void k_prep(
    const float* __restrict__ Wqkv, const float* __restrict__ Wout,
    const float* __restrict__ W1, const float* __restrict__ b1,
    _Float16* __restrict__ Wt, _Float16* __restrict__ Wot,
    __half* __restrict__ Tx, __half* __restrict__ Ty) {
  __shared__ float Tt[32 * 33];
  const int t = threadIdx.x;
  const int bid = blockIdx.x;
  if (bid >= 1024) {                     // hidden-layer tables
    int gid = (bid - 1024) * 256 + t;
    int e = gid >> 5, c = gid & 31;
    float u = -UMAXV + (2.0f * UMAXV) * (float)e / (float)(TBL - 1);
    const int xpart = (c < 16);
    const int col = c & 15;
    const int base = xpart ? 0 : 65;
    float sum = u * W1[base * 16 + col] + (xpart ? b1[col] : 0.0f);
    float s1, c1;
    sincosf(u * 3.14159265358979323846f, &s1, &c1);
    float sk = s1, ck = c1;
    for (int k = 1; k <= 32; ++k) {
      sum += sk * W1[(base + k) * 16 + col] + ck * W1[(base + 32 + k) * 16 + col];
      float ns = sk * c1 + ck * s1;
      ck = ck * c1 - sk * s1;
      sk = ns;
    }
    (xpart ? Tx : Ty)[e * 16 + col] = __float2half(sum);
    return;
  }
  int k0, n0, ncols;
  const float* W;
  _Float16* O;
  if (bid < 768) {                       // Wqkv: 512x1536 -> Wt[1536][512]
    k0 = (bid / 48) * 32; n0 = (bid % 48) * 32; ncols = 1536;
    W = Wqkv; O = Wt;
  } else {                               // Wout: 512x512 -> Wot[512][512]
    int tile = bid - 768;
    k0 = (tile / 16) * 32; n0 = (tile % 16) * 32; ncols = 512;
    W = Wout; O = Wot;
  }
  {
    int kl = t >> 3, nl = (t & 7) * 4;
    float4 v = *(const float4*)&W[(k0 + kl) * ncols + n0 + nl];
    Tt[kl * 33 + nl + 0] = v.x;
    Tt[kl * 33 + nl + 1] = v.y;
    Tt[kl * 33 + nl + 2] = v.z;
    Tt[kl * 33 + nl + 3] = v.w;
  }
  __syncthreads();
  {
    int nl = t >> 3, kq = (t & 7) * 4;
    ushort4 h;
    h.x = __builtin_bit_cast(unsigned short, (_Float16)Tt[(kq + 0) * 33 + nl]);
    h.y = __builtin_bit_cast(unsigned short, (_Float16)Tt[(kq + 1) * 33 + nl]);
    h.z = __builtin_bit_cast(unsigned short, (_Float16)Tt[(kq + 2) * 33 + nl]);
    h.w = __builtin_bit_cast(unsigned short, (_Float16)Tt[(kq + 3) * 33 + nl]);
    *(ushort4*)&O[(n0 + nl) * 512 + k0 + kq] = h;
  }
}

// ---------------- K_fused: QKV MFMA GEMM (bid<192) + RPE bias (bid>=192) ----
__global__ __launch_bounds__(512) void k_fused(
    const float* __restrict__ x, const _Float16* __restrict__ Wt,
    _Float16* __restrict__ q16, _Float16* __restrict__ k16,
    _Float16* __restrict__ vt16,
    const float* __restrict__ pos,
    const __half* __restrict__ Tx, const __half* __restrict__ Ty,
    const float* __restrict__ W2, const float* __restrict__ b2,
    _Float16* __restrict__ bias) {
  __shared__ __align__(16) unsigned short SM[16384];   // 32 KB (qkv path only)
  const int bid = blockIdx.x;
  const int t = threadIdx.x;

  if (bid < 192) {
    // ---- QKV GEMM: 128x64 tile, 8 waves (32x32 per wave), K=512 -----------
    _Float16* Ah = (_Float16*)SM;            // [128][64] = 16 KB
    _Float16* Bh = (_Float16*)SM + 8192;     // [64][64]  = 8 KB
    const int mt = bid / 24, nt = bid % 24;
    const int m0 = mt * 128, n0 = nt * 64;
    const int w = t >> 6, lane = t & 63, blk = lane >> 4, jc = lane & 15;
    const int mw = (w & 3) * 32, nw = (w >> 2) * 32;
    const int sa = t >> 3, sq = t & 7;

    f32x4 acc[2][2];
    #pragma unroll
    for (int i = 0; i < 2; ++i)
      #pragma unroll
      for (int j = 0; j < 2; ++j) acc[i][j] = f32x4{0.f, 0.f, 0.f, 0.f};

    float4 pax[2][2];
    f16x8 pbv;
    #pragma unroll
    for (int c = 0; c < 2; ++c) {
      const float* xp = &x[(m0 + sa + c * 64) * 512 + sq * 8];
      pax[c][0] = *(const float4*)xp;
      pax[c][1] = *(const float4*)(xp + 4);
    }
    pbv = *(const f16x8*)&Wt[(n0 + sa) * 512 + sq * 8];

    for (int it = 0; it < 8; ++it) {
      #pragma unroll
      for (int c = 0; c < 2; ++c)
        *(f16x8*)&Ah[swq(sa + c * 64, sq)] = cvt8(pax[c][0], pax[c][1]);
      *(f16x8*)&Bh[swq(sa, sq)] = pbv;
      __syncthreads();
      if (it < 7) {
        int k0 = (it + 1) * 64;
        #pragma unroll
        for (int c = 0; c < 2; ++c) {
          const float* xp = &x[(m0 + sa + c * 64) * 512 + k0 + sq * 8];
          pax[c][0] = *(const float4*)xp;
          pax[c][1] = *(const float4*)(xp + 4);
        }
        pbv = *(const f16x8*)&Wt[(n0 + sa) * 512 + k0 + sq * 8];
      }
      #pragma unroll
      for (int h = 0; h < 2; ++h) {
        int q = h * 4 + blk;
        f16x8 a0 = *(const f16x8*)&Ah[swq(mw + jc, q)];
        f16x8 a1 = *(const f16x8*)&Ah[swq(mw + 16 + jc, q)];
        f16x8 b0 = *(const f16x8*)&Bh[swq(nw + jc, q)];
        f16x8 b1 = *(const f16x8*)&Bh[swq(nw + 16 + jc, q)];
        acc[0][0] = __builtin_amdgcn_mfma_f32_16x16x32_f16(a0, b0, acc[0][0], 0, 0, 0);
        acc[0][1] = __builtin_amdgcn_mfma_f32_16x16x32_f16(a0, b1, acc[0][1], 0, 0, 0);
        acc[1][0] = __builtin_amdgcn_mfma_f32_16x16x32_f16(a1, b0, acc[1][0], 0, 0, 0);
        acc[1][1] = __builtin_amdgcn_mfma_f32_16x16x32_f16(a1, b1, acc[1][1], 0, 0, 0);
      }
      __syncthreads();
    }
    const int sec = n0 >> 9;
    const int hh_ = (n0 >> 6) & 7;
    if (sec < 2) {
      _Float16* dst = (sec == 0) ? q16 : k16;
      const float scl = (sec == 0) ? 0.125f : 1.0f;
      #pragma unroll
      for (int i = 0; i < 2; ++i)
        #pragma unroll
        for (int j = 0; j < 2; ++j)
          #pragma unroll
          for (int r = 0; r < 4; ++r) {
            int tok = m0 + mw + i * 16 + blk * 4 + r;
            int b = tok >> 9, nn = tok & 511;
            int d = nw + j * 16 + jc;
            dst[((b * 8 + hh_) * 512 + nn) * 64 + d] = (_Float16)(acc[i][j][r] * scl);
          }
    } else {
      _Float16* T = (_Float16*)SM;       // [64 d][136 tok]
      #pragma unroll
      for (int i = 0; i < 2; ++i)
        #pragma unroll
        for (int j = 0; j < 2; ++j)
          #pragma unroll
          for (int r = 0; r < 4; ++r)
            T[(nw + j * 16 + jc) * 136 + mw + i * 16 + blk * 4 + r] =
                (_Float16)acc[i][j][r];
      __syncthreads();
      const int d = t >> 3, tq = t & 7;
      const int b = m0 >> 9, nb = m0 & 511;
      #pragma unroll
      for (int c = 0; c < 2; ++c) {
        int qd = tq + c * 8;
        f16x8 vv = *(const f16x8*)&T[d * 136 + qd * 8];
        *(f16x8*)&vt16[((b * 8 + hh_) * 64 + d) * 512 + nb + qd * 8] = vv;
      }
    }
    return;
  }

  // ---- RPE bias path: one pair per thread --------------------------------
  const int gid = (bid - 192) * 512 + t;   // < 524288
  const int b = gid >> 18;
  const int i = (gid >> 9) & 511;
  const int j = gid & 511;
  const float pix = pos[(b * 512 + i) * 2 + 0];
  const float piy = pos[(b * 512 + i) * 2 + 1];
  const float pjx = pos[(b * 512 + j) * 2 + 0];
  const float pjy = pos[(b * 512 + j) * 2 + 1];
  float txv = (pjx - pix) * 0.1f; float ux = txv / (1.0f + fabsf(txv));
  float tyv = (pjy - piy) * 0.1f; float uy = tyv / (1.0f + fabsf(tyv));
  const float invstep = (float)(TBL - 1) / (2.0f * UMAXV);
  float fx = (ux + UMAXV) * invstep;
  int ix = (int)fx; ix = min(max(ix, 0), TBL - 2);
  float wx = fx - (float)ix;
  float fy = (uy + UMAXV) * invstep;
  int iy = (int)fy; iy = min(max(iy, 0), TBL - 2);
  float wy = fy - (float)iy;

  __half hx0[16], hx1[16], hy0[16], hy1[16];
  *(uint4*)&hx0[0] = *(const uint4*)&Tx[ix * 16];
  *(uint4*)&hx0[8] = *(const uint4*)&Tx[ix * 16 + 8];
  *(uint4*)&hx1[0] = *(const uint4*)&Tx[(ix + 1) * 16];
  *(uint4*)&hx1[8] = *(const uint4*)&Tx[(ix + 1) * 16 + 8];
  *(uint4*)&hy0[0] = *(const uint4*)&Ty[iy * 16];
  *(uint4*)&hy0[8] = *(const uint4*)&Ty[iy * 16 + 8];
  *(uint4*)&hy1[0] = *(const uint4*)&Ty[(iy + 1) * 16];
  *(uint4*)&hy1[8] = *(const uint4*)&Ty[(iy + 1) * 16 + 8];

  float o[8];
  #pragma unroll
  for (int c = 0; c < 8; ++c) o[c] = b2[c];
  #pragma unroll
  for (int r = 0; r < 16; ++r) {
    float ax = __half2float(hx0[r]);
    float bx = __half2float(hx1[r]);
    float ay = __half2float(hy0[r]);
    float by = __half2float(hy1[r]);
    float hv = fmaf(wx, bx - ax, ax) + fmaf(wy, by - ay, ay);
    float z = hv * 0.70710678118654752f;
    float az = fabsf(z);
    float tt = __builtin_amdgcn_rcpf(fmaf(0.3275911f, az, 1.0f));
    float poly = ((((1.061405429f * tt - 1.453152027f) * tt + 1.421413741f) * tt
                   - 0.284496736f) * tt + 0.254829592f) * tt;
    float ex = __expf(-z * z);
    float erfv = copysignf(fmaf(-poly, ex, 1.0f), z);
    float g = 0.5f * hv * (1.0f + erfv);
    #pragma unroll
    for (int c = 0; c < 8; ++c)
      o[c] = fmaf(g, W2[r * 8 + c], o[c]);
  }
  #pragma unroll
  for (int c = 0; c < 8; ++c)
    bias[((size_t)(b * 8 + c) * 512 + i) * 512 + j] = (_Float16)o[c];
}

// ---------------- K_attn2: fused flash attention + output projection --------
// grid 64 = (b, 16-row i-tile); 8 waves; wave w = head w, full j=512 loop.
// Then block-level out-GEMM from LDS ao tile.
__global__ __launch_bounds__(512) void k_attn2(
    const _Float16* __restrict__ q16, const _Float16* __restrict__ k16,
    const _Float16* __restrict__ vt16, const _Float16* __restrict__ bias,
    const _Float16* __restrict__ Wot, const float* __restrict__ bout,
    float* __restrict__ out) {
  __shared__ __align__(16) _Float16 psu[8 * 512];    // per-wave P [16][32]
  __shared__ __align__(16) _Float16 bstw[8 * 512];   // per-wave bias [16][32]
  __shared__ __align__(16) _Float16 aos[16 * 512];   // swizzled ao tile (fp16)

  const int bid = blockIdx.x;            // 64 = b*32 + it
  const int it = bid & 31, b = bid >> 5;
  const int i0 = it * 16;
  const int tid = threadIdx.x;
  const int w = tid >> 6, lane = tid & 63;
  const int blk = lane >> 4, jc = lane & 15;
  const int bh = b * 8 + w;              // wave = head

  const int qoff = (bh * 512 + i0 + jc) * 64 + blk * 8;
  const f16x8 qa0 = *(const f16x8*)&q16[qoff];
  const f16x8 qa1 = *(const f16x8*)&q16[qoff + 32];

  float m[4] = {-1e30f, -1e30f, -1e30f, -1e30f};
  float l[4] = {0.f, 0.f, 0.f, 0.f};
  f32x4 o[4];
  #pragma unroll
  for (int dt = 0; dt < 4; ++dt) o[dt] = f32x4{0.f, 0.f, 0.f, 0.f};

  _Float16* pw = &psu[w * 512];
  _Float16* bw = &bstw[w * 512];
  const int brow = lane >> 2, bcol = (lane & 3) * 8;
  const _Float16* bgp = bias + ((size_t)(bh * 512 + i0)) * 512;

  for (int js = 0; js < 16; ++js) {
    const int j0 = js * 32;
    // stage this wave's 16x32 bias chunk (wave-private, no barrier)
    *(f16x8*)&bw[brow * 32 + bcol] = *(const f16x8*)&bgp[brow * 512 + j0 + bcol];

    const int rA = (bh * 512 + j0 + jc) * 64 + blk * 8;
    const int rB = rA + 16 * 64;
    f16x8 kA0 = *(const f16x8*)&k16[rA];
    f16x8 kA1 = *(const f16x8*)&k16[rA + 32];
    f16x8 kB0 = *(const f16x8*)&k16[rB];
    f16x8 kB1 = *(const f16x8*)&k16[rB + 32];

    f32x4 aA = {0.f, 0.f, 0.f, 0.f};
    aA = __builtin_amdgcn_mfma_f32_16x16x32_f16(qa0, kA0, aA, 0, 0, 0);
    aA = __builtin_amdgcn_mfma_f32_16x16x32_f16(qa1, kA1, aA, 0, 0, 0);
    f32x4 aB = {0.f, 0.f, 0.f, 0.f};
    aB = __builtin_amdgcn_mfma_f32_16x16x32_f16(qa0, kB0, aB, 0, 0, 0);
    aB = __builtin_amdgcn_mfma_f32_16x16x32_f16(qa1, kB1, aB, 0, 0, 0);

    float sA[4], sB[4], sc[4];
    #pragma unroll
    for (int r = 0; r < 4; ++r) {
      const int br = (blk * 4 + r) * 32;
      sA[r] = aA[r] + (float)bw[br + jc];
      sB[r] = aB[r] + (float)bw[br + 16 + jc];
    }
    #pragma unroll
    for (int r = 0; r < 4; ++r) {
      float mx = fmaxf(sA[r], sB[r]);
      mx = fmaxf(mx, __shfl_xor(mx, 1, 64));
      mx = fmaxf(mx, __shfl_xor(mx, 2, 64));
      mx = fmaxf(mx, __shfl_xor(mx, 4, 64));
      mx = fmaxf(mx, __shfl_xor(mx, 8, 64));
      float mn = fmaxf(m[r], mx);
      sc[r] = __expf(m[r] - mn);
      m[r] = mn;
      float pA = __expf(sA[r] - mn);
      float pB = __expf(sB[r] - mn);
      float ps = pA + pB;
      ps += __shfl_xor(ps, 1, 64);
      ps += __shfl_xor(ps, 2, 64);
      ps += __shfl_xor(ps, 4, 64);
      ps += __shfl_xor(ps, 8, 64);
      l[r] = l[r] * sc[r] + ps;
      pw[(blk * 4 + r) * 32 + jc] = (_Float16)pA;
      pw[(blk * 4 + r) * 32 + 16 + jc] = (_Float16)pB;
    }
    #pragma unroll
    for (int dt = 0; dt < 4; ++dt)
      #pragma unroll
      for (int r = 0; r < 4; ++r)
        o[dt][r] *= sc[r];
    f16x8 pf = *(const f16x8*)&pw[jc * 32 + blk * 8];
    #pragma unroll
    for (int dt = 0; dt < 4; ++dt) {
      const f16x8 vh = *(const f16x8*)&vt16[(bh * 64 + dt * 16 + jc) * 512 + j0 + blk * 8];
      o[dt] = __builtin_amdgcn_mfma_f32_16x16x32_f16(pf, vh, o[dt], 0, 0, 0);
    }
  }

  // epilogue: normalized o -> swizzled LDS ao tile [16 rows][512 cols]
  float inv[4];
  #pragma unroll
  for (int r = 0; r < 4; ++r) inv[r] = 1.0f / l[r];
  #pragma unroll
  for (int dt = 0; dt < 4; ++dt)
    #pragma unroll
    for (int r = 0; r < 4; ++r) {
      int row = blk * 4 + r;
      int col = w * 64 + dt * 16 + jc;
      aos[row * 512 + (((col >> 3) ^ (row & 7)) << 3) + (col & 7)] =
          (_Float16)(o[dt][r] * inv[r]);
    }
  __syncthreads();

  // out-GEMM: out[16 rows][n = w*64 .. w*64+64) = aos @ Wot^T + bout
  f32x4 acc[4];
  #pragma unroll
  for (int ns = 0; ns < 4; ++ns) acc[ns] = f32x4{0.f, 0.f, 0.f, 0.f};
  #pragma unroll
  for (int ks = 0; ks < 16; ++ks) {
    const f16x8 af = *(const f16x8*)&aos[jc * 512 + (((ks * 4 + blk) ^ (jc & 7)) << 3)];
    #pragma unroll
    for (int ns = 0; ns < 4; ++ns) {
      const f16x8 bf =
          *(const f16x8*)&Wot[(w * 64 + ns * 16 + jc) * 512 + ks * 32 + blk * 8];
      acc[ns] = __builtin_amdgcn_mfma_f32_16x16x32_f16(af, bf, acc[ns], 0, 0, 0);
    }
  }
  #pragma unroll
  for (int ns = 0; ns < 4; ++ns) {
    int n = w * 64 + ns * 16 + jc;
    float bb = bout[n];
    #pragma unroll
    for (int r = 0; r < 4; ++r) {
      int row = i0 + blk * 4 + r;
      out[(b * 512 + row) * 512 + n] = acc[ns][r] + bb;
    }
  }
}

extern "C" void kernel_launch(void* const* d_in, const int* in_sizes, int n_in,
                              void* d_out, int out_size, void* d_ws, size_t ws_size,
                              hipStream_t stream) {
  const float* x    = (const float*)d_in[0];
  const float* pos  = (const float*)d_in[1];
  const float* Wqkv = (const float*)d_in[2];
  const float* Wout = (const float*)d_in[3];
  const float* bout = (const float*)d_in[4];
  const float* W1   = (const float*)d_in[5];
  const float* b1   = (const float*)d_in[6];
  const float* W2   = (const float*)d_in[7];
  const float* b2   = (const float*)d_in[8];
  float* out = (float*)d_out;
  char* base = (char*)d_ws;

  __half* Tx       = (__half*)(base);                       // 16 KB
  __half* Ty       = (__half*)(base + 16384);               // 16 KB
  _Float16* Wt     = (_Float16*)(base + 32768);             // 1.5 MB
  _Float16* Wot    = (_Float16*)(base + 1605632);           // 512 KB
  _Float16* q16    = (_Float16*)(base + 2129920);           // 1 MB
  _Float16* k16    = (_Float16*)(base + 3178496);           // 1 MB
  _Float16* vt16   = (_Float16*)(base + 4227072);           // 1 MB
  _Float16* bias16 = (_Float16*)(base + 5275648);           // 8 MB

  hipLaunchKernelGGL(k_prep, dim3(1088), dim3(256), 0, stream,
                     Wqkv, Wout, W1, b1, Wt, Wot, Tx, Ty);
  hipLaunchKernelGGL(k_fused, dim3(1216), dim3(512), 0, stream,
                     x, Wt, q16, k16, vt16, pos, Tx, Ty, W2, b2, bias16);
  hipLaunchKernelGGL(k_attn2, dim3(64), dim3(512), 0, stream,
                     q16, k16, vt16, bias16, Wot, bout, out);
}

// Round 9
// 42.955 us; speedup vs baseline: 1.6843x; 1.6843x over previous
//
#include <hip/hip_runtime.h>
#include <hip/hip_fp16.h>
#include <math.h>

typedef __attribute__((ext_vector_type(8))) _Float16 f16x8;
typedef __attribute__((ext_vector_type(4))) float f32x4;

#define TBL 512
#define UMAXV (1.0f/11.0f)

// swizzled 16B-quad element index within a [rows][64-f16] LDS tile
__device__ __forceinline__ int swq(int row, int q) {
  return row * 64 + ((q ^ (row & 7)) << 3);
}
__device__ __forceinline__ f16x8 cvt8(float4 a, float4 b) {
  f16x8 r;
  r[0] = (_Float16)a.x; r[1] = (_Float16)a.y;
  r[2] = (_Float16)a.z; r[3] = (_Float16)a.w;
  r[4] = (_Float16)b.x; r[5] = (_Float16)b.y;
  r[6] = (_Float16)b.z; r[7] = (_Float16)b.w;
  return r;
}

// ---------------- K_prep: transpose+cvt Wqkv/Wout to fp16; build tables -----
__global__ __launch_bounds__(256) void k_prep(
    const float* __restrict__ Wqkv, const float* __restrict__ Wout,
    const float* __restrict__ W1, const float* __restrict__ b1,
    _Float16* __restrict__ Wt, _Float16* __restrict__ Wot,
    __half* __restrict__ Tx, __half* __restrict__ Ty) {
  __shared__ float Tt[32 * 33];
  const int t = threadIdx.x;
  const int bid = blockIdx.x;
  if (bid >= 1024) {                     // hidden-layer tables
    int gid = (bid - 1024) * 256 + t;
    int e = gid >> 5, c = gid & 31;
    float u = -UMAXV + (2.0f * UMAXV) * (float)e / (float)(TBL - 1);
    const int xpart = (c < 16);
    const int col = c & 15;
    const int base = xpart ? 0 : 65;
    float sum = u * W1[base * 16 + col] + (xpart ? b1[col] : 0.0f);
    float s1, c1;
    sincosf(u * 3.14159265358979323846f, &s1, &c1);
    float sk = s1, ck = c1;
    for (int k = 1; k <= 32; ++k) {
      sum += sk * W1[(base + k) * 16 + col] + ck * W1[(base + 32 + k) * 16 + col];
      float ns = sk * c1 + ck * s1;
      ck = ck * c1 - sk * s1;
      sk = ns;
    }
    (xpart ? Tx : Ty)[e * 16 + col] = __float2half(sum);
    return;
  }
  int k0, n0, ncols;
  const float* W;
  _Float16* O;
  if (bid < 768) {                       // Wqkv: 512x1536 -> Wt[1536][512]
    k0 = (bid / 48) * 32; n0 = (bid % 48) * 32; ncols = 1536;
    W = Wqkv; O = Wt;
  } else {                               // Wout: 512x512 -> Wot[512][512]
    int tile = bid - 768;
    k0 = (tile / 16) * 32; n0 = (tile % 16) * 32; ncols = 512;
    W = Wout; O = Wot;
  }
  {
    int kl = t >> 3, nl = (t & 7) * 4;
    float4 v = *(const float4*)&W[(k0 + kl) * ncols + n0 + nl];
    Tt[kl * 33 + nl + 0] = v.x;
    Tt[kl * 33 + nl + 1] = v.y;
    Tt[kl * 33 + nl + 2] = v.z;
    Tt[kl * 33 + nl + 3] = v.w;
  }
  __syncthreads();
  {
    int nl = t >> 3, kq = (t & 7) * 4;
    ushort4 h;
    h.x = __builtin_bit_cast(unsigned short, (_Float16)Tt[(kq + 0) * 33 + nl]);
    h.y = __builtin_bit_cast(unsigned short, (_Float16)Tt[(kq + 1) * 33 + nl]);
    h.z = __builtin_bit_cast(unsigned short, (_Float16)Tt[(kq + 2) * 33 + nl]);
    h.w = __builtin_bit_cast(unsigned short, (_Float16)Tt[(kq + 3) * 33 + nl]);
    *(ushort4*)&O[(n0 + nl) * 512 + k0 + kq] = h;
  }
}

// ---------------- K_fused: QKV MFMA GEMM (bid<192) + RPE bias (bid>=192) ----
__global__ __launch_bounds__(512) void k_fused(
    const float* __restrict__ x, const _Float16* __restrict__ Wt,
    _Float16* __restrict__ q16, _Float16* __restrict__ k16,
    _Float16* __restrict__ vt16,
    const float* __restrict__ pos,
    const __half* __restrict__ Tx, const __half* __restrict__ Ty,
    const float* __restrict__ W2, const float* __restrict__ b2,
    _Float16* __restrict__ bias) {
  __shared__ __align__(16) unsigned short SM[16384];   // 32 KB (qkv path only)
  const int bid = blockIdx.x;
  const int t = threadIdx.x;

  if (bid < 192) {
    // ---- QKV GEMM: 128x64 tile, 8 waves (32x32/wave), 2-deep prefetch -----
    // XCD swizzle: group the 24 nt-blocks of one mt on one XCD
    const int gb = (bid & 7) * 24 + (bid >> 3);
    _Float16* Ah = (_Float16*)SM;            // [128][64] = 16 KB
    _Float16* Bh = (_Float16*)SM + 8192;     // [64][64]  = 8 KB
    const int mt = gb / 24, nt = gb % 24;
    const int m0 = mt * 128, n0 = nt * 64;
    const int w = t >> 6, lane = t & 63, blk = lane >> 4, jc = lane & 15;
    const int mw = (w & 3) * 32, nw = (w >> 2) * 32;
    const int sa = t >> 3, sq = t & 7;

    f32x4 acc[2][2];
    #pragma unroll
    for (int i = 0; i < 2; ++i)
      #pragma unroll
      for (int j = 0; j < 2; ++j) acc[i][j] = f32x4{0.f, 0.f, 0.f, 0.f};

    float4 pax[2][2][2];
    f16x8 pbv[2];
    #pragma unroll
    for (int s = 0; s < 2; ++s) {
      #pragma unroll
      for (int c = 0; c < 2; ++c) {
        const float* xp = &x[(m0 + sa + c * 64) * 512 + s * 64 + sq * 8];
        pax[s][c][0] = *(const float4*)xp;
        pax[s][c][1] = *(const float4*)(xp + 4);
      }
      pbv[s] = *(const f16x8*)&Wt[(n0 + sa) * 512 + s * 64 + sq * 8];
    }

    for (int it = 0; it < 8; ++it) {
      const int slot = it & 1;
      #pragma unroll
      for (int c = 0; c < 2; ++c)
        *(f16x8*)&Ah[swq(sa + c * 64, sq)] = cvt8(pax[slot][c][0], pax[slot][c][1]);
      *(f16x8*)&Bh[swq(sa, sq)] = pbv[slot];
      __syncthreads();
      if (it < 6) {
        int k0 = (it + 2) * 64;
        #pragma unroll
        for (int c = 0; c < 2; ++c) {
          const float* xp = &x[(m0 + sa + c * 64) * 512 + k0 + sq * 8];
          pax[slot][c][0] = *(const float4*)xp;
          pax[slot][c][1] = *(const float4*)(xp + 4);
        }
        pbv[slot] = *(const f16x8*)&Wt[(n0 + sa) * 512 + k0 + sq * 8];
      }
      #pragma unroll
      for (int h = 0; h < 2; ++h) {
        int q = h * 4 + blk;
        f16x8 a0 = *(const f16x8*)&Ah[swq(mw + jc, q)];
        f16x8 a1 = *(const f16x8*)&Ah[swq(mw + 16 + jc, q)];
        f16x8 b0 = *(const f16x8*)&Bh[swq(nw + jc, q)];
        f16x8 b1 = *(const f16x8*)&Bh[swq(nw + 16 + jc, q)];
        acc[0][0] = __builtin_amdgcn_mfma_f32_16x16x32_f16(a0, b0, acc[0][0], 0, 0, 0);
        acc[0][1] = __builtin_amdgcn_mfma_f32_16x16x32_f16(a0, b1, acc[0][1], 0, 0, 0);
        acc[1][0] = __builtin_amdgcn_mfma_f32_16x16x32_f16(a1, b0, acc[1][0], 0, 0, 0);
        acc[1][1] = __builtin_amdgcn_mfma_f32_16x16x32_f16(a1, b1, acc[1][1], 0, 0, 0);
      }
      __syncthreads();
    }
    const int sec = n0 >> 9;
    const int hh_ = (n0 >> 6) & 7;
    if (sec < 2) {
      _Float16* dst = (sec == 0) ? q16 : k16;
      const float scl = (sec == 0) ? 0.125f : 1.0f;
      #pragma unroll
      for (int i = 0; i < 2; ++i)
        #pragma unroll
        for (int j = 0; j < 2; ++j)
          #pragma unroll
          for (int r = 0; r < 4; ++r) {
            int tok = m0 + mw + i * 16 + blk * 4 + r;
            int b = tok >> 9, nn = tok & 511;
            int d = nw + j * 16 + jc;
            dst[((b * 8 + hh_) * 512 + nn) * 64 + d] = (_Float16)(acc[i][j][r] * scl);
          }
    } else {
      _Float16* T = (_Float16*)SM;       // [64 d][136 tok]
      #pragma unroll
      for (int i = 0; i < 2; ++i)
        #pragma unroll
        for (int j = 0; j < 2; ++j)
          #pragma unroll
          for (int r = 0; r < 4; ++r)
            T[(nw + j * 16 + jc) * 136 + mw + i * 16 + blk * 4 + r] =
                (_Float16)acc[i][j][r];
      __syncthreads();
      const int d = t >> 3, tq = t & 7;
      const int b = m0 >> 9, nb = m0 & 511;
      #pragma unroll
      for (int c = 0; c < 2; ++c) {
        int qd = tq + c * 8;
        f16x8 vv = *(const f16x8*)&T[d * 136 + qd * 8];
        *(f16x8*)&vt16[((b * 8 + hh_) * 64 + d) * 512 + nb + qd * 8] = vv;
      }
    }
    return;
  }

  // ---- RPE bias path: one pair per thread --------------------------------
  const int gid = (bid - 192) * 512 + t;   // < 524288
  const int b = gid >> 18;
  const int i = (gid >> 9) & 511;
  const int j = gid & 511;
  const float pix = pos[(b * 512 + i) * 2 + 0];
  const float piy = pos[(b * 512 + i) * 2 + 1];
  const float pjx = pos[(b * 512 + j) * 2 + 0];
  const float pjy = pos[(b * 512 + j) * 2 + 1];
  float txv = (pjx - pix) * 0.1f; float ux = txv / (1.0f + fabsf(txv));
  float tyv = (pjy - piy) * 0.1f; float uy = tyv / (1.0f + fabsf(tyv));
  const float invstep = (float)(TBL - 1) / (2.0f * UMAXV);
  float fx = (ux + UMAXV) * invstep;
  int ix = (int)fx; ix = min(max(ix, 0), TBL - 2);
  float wx = fx - (float)ix;
  float fy = (uy + UMAXV) * invstep;
  int iy = (int)fy; iy = min(max(iy, 0), TBL - 2);
  float wy = fy - (float)iy;

  __half hx0[16], hx1[16], hy0[16], hy1[16];
  *(uint4*)&hx0[0] = *(const uint4*)&Tx[ix * 16];
  *(uint4*)&hx0[8] = *(const uint4*)&Tx[ix * 16 + 8];
  *(uint4*)&hx1[0] = *(const uint4*)&Tx[(ix + 1) * 16];
  *(uint4*)&hx1[8] = *(const uint4*)&Tx[(ix + 1) * 16 + 8];
  *(uint4*)&hy0[0] = *(const uint4*)&Ty[iy * 16];
  *(uint4*)&hy0[8] = *(const uint4*)&Ty[iy * 16 + 8];
  *(uint4*)&hy1[0] = *(const uint4*)&Ty[(iy + 1) * 16];
  *(uint4*)&hy1[8] = *(const uint4*)&Ty[(iy + 1) * 16 + 8];

  float o[8];
  #pragma unroll
  for (int c = 0; c < 8; ++c) o[c] = b2[c];
  #pragma unroll
  for (int r = 0; r < 16; ++r) {
    float ax = __half2float(hx0[r]);
    float bx = __half2float(hx1[r]);
    float ay = __half2float(hy0[r]);
    float by = __half2float(hy1[r]);
    float hv = fmaf(wx, bx - ax, ax) + fmaf(wy, by - ay, ay);
    float z = hv * 0.70710678118654752f;
    float az = fabsf(z);
    float tt = __builtin_amdgcn_rcpf(fmaf(0.3275911f, az, 1.0f));
    float poly = ((((1.061405429f * tt - 1.453152027f) * tt + 1.421413741f) * tt
                   - 0.284496736f) * tt + 0.254829592f) * tt;
    float ex = __expf(-z * z);
    float erfv = copysignf(fmaf(-poly, ex, 1.0f), z);
    float g = 0.5f * hv * (1.0f + erfv);
    #pragma unroll
    for (int c = 0; c < 8; ++c)
      o[c] = fmaf(g, W2[r * 8 + c], o[c]);
  }
  #pragma unroll
  for (int c = 0; c < 8; ++c)
    bias[((size_t)(b * 8 + c) * 512 + i) * 512 + j] = (_Float16)o[c];
}

// ---------------- K3: MFMA flash attention (fp16, staggered prefetch) -------
__global__ __launch_bounds__(512) void k_attn(
    const _Float16* __restrict__ q16, const _Float16* __restrict__ k16,
    const _Float16* __restrict__ vt16, const _Float16* __restrict__ bias,
    _Float16* __restrict__ ao16) {
  __shared__ __align__(16) _Float16 psu[8 * 512];      // per-wave P [16][32]
  __shared__ __align__(16) float olds[8 * 16 * 65];    // aliased: bst[16][520] f16
  __shared__ float mls[8 * 16 * 2];
  _Float16* bst = (_Float16*)olds;

  // XCD swizzle: 2 (b,h) groups per XCD
  const int lb = (blockIdx.x & 7) * 64 + (blockIdx.x >> 3);
  const int it = lb & 31, h = (lb >> 5) & 7, b = lb >> 8;
  const int i0 = it * 16;
  const int bh = b * 8 + h;
  const int tid = threadIdx.x;
  const int w = tid >> 6, lane = tid & 63;
  const int blk = lane >> 4, jc = lane & 15;

  // stage the 16x512 bias slice into LDS (rows padded to 520)
  {
    const _Float16* bgp = bias + ((size_t)(bh * 512 + i0)) * 512;
    int brow = tid >> 5, bc = (tid & 31) * 16;
    *(f16x8*)&bst[brow * 520 + bc]     = *(const f16x8*)&bgp[brow * 512 + bc];
    *(f16x8*)&bst[brow * 520 + bc + 8] = *(const f16x8*)&bgp[brow * 512 + bc + 8];
  }

  const int qoff = (bh * 512 + i0 + jc) * 64 + blk * 8;
  const f16x8 qa0 = *(const f16x8*)&q16[qoff];
  const f16x8 qa1 = *(const f16x8*)&q16[qoff + 32];

  // hoist jt=0 K/V loads above the barrier (issue early)
  const int j00 = w * 64;
  f16x8 k0A0, k0A1, k0B0, k0B1, v0[4];
  {
    const int rA = (bh * 512 + j00 + jc) * 64 + blk * 8;
    const int rB = rA + 16 * 64;
    k0A0 = *(const f16x8*)&k16[rA];
    k0A1 = *(const f16x8*)&k16[rA + 32];
    k0B0 = *(const f16x8*)&k16[rB];
    k0B1 = *(const f16x8*)&k16[rB + 32];
    #pragma unroll
    for (int dt = 0; dt < 4; ++dt)
      v0[dt] = *(const f16x8*)&vt16[(bh * 64 + dt * 16 + jc) * 512 + j00 + blk * 8];
  }

  float m[4] = {-1e30f, -1e30f, -1e30f, -1e30f};
  float l[4] = {0.f, 0.f, 0.f, 0.f};
  f32x4 o[4];
  #pragma unroll
  for (int dt = 0; dt < 4; ++dt) o[dt] = f32x4{0.f, 0.f, 0.f, 0.f};

  _Float16* pw = &psu[w * 512];
  __syncthreads();   // bias staged

  // =========== jt = 0 ===========
  f32x4 aA = {0.f, 0.f, 0.f, 0.f};
  aA = __builtin_amdgcn_mfma_f32_16x16x32_f16(qa0, k0A0, aA, 0, 0, 0);
  aA = __builtin_amdgcn_mfma_f32_16x16x32_f16(qa1, k0A1, aA, 0, 0, 0);
  f32x4 aB = {0.f, 0.f, 0.f, 0.f};
  aB = __builtin_amdgcn_mfma_f32_16x16x32_f16(qa0, k0B0, aB, 0, 0, 0);
  aB = __builtin_amdgcn_mfma_f32_16x16x32_f16(qa1, k0B1, aB, 0, 0, 0);

  // issue jt=1 K/V loads now; softmax below hides their latency
  const int j01 = w * 64 + 32;
  f16x8 k1A0, k1A1, k1B0, k1B1, v1[4];
  {
    const int rA = (bh * 512 + j01 + jc) * 64 + blk * 8;
    const int rB = rA + 16 * 64;
    k1A0 = *(const f16x8*)&k16[rA];
    k1A1 = *(const f16x8*)&k16[rA + 32];
    k1B0 = *(const f16x8*)&k16[rB];
    k1B1 = *(const f16x8*)&k16[rB + 32];
    #pragma unroll
    for (int dt = 0; dt < 4; ++dt)
      v1[dt] = *(const f16x8*)&vt16[(bh * 64 + dt * 16 + jc) * 512 + j01 + blk * 8];
  }

  {
    float sA[4], sB[4], sc[4];
    #pragma unroll
    for (int r = 0; r < 4; ++r) {
      const int br = (blk * 4 + r) * 520;
      sA[r] = aA[r] + (float)bst[br + j00 + jc];
      sB[r] = aB[r] + (float)bst[br + j00 + 16 + jc];
    }
    #pragma unroll
    for (int r = 0; r < 4; ++r) {
      float mx = fmaxf(sA[r], sB[r]);
      mx = fmaxf(mx, __shfl_xor(mx, 1, 64));
      mx = fmaxf(mx, __shfl_xor(mx, 2, 64));
      mx = fmaxf(mx, __shfl_xor(mx, 4, 64));
      mx = fmaxf(mx, __shfl_xor(mx, 8, 64));
      float mn = fmaxf(m[r], mx);
      sc[r] = __expf(m[r] - mn);
      m[r] = mn;
      float pA = __expf(sA[r] - mn);
      float pB = __expf(sB[r] - mn);
      float ps = pA + pB;
      ps += __shfl_xor(ps, 1, 64);
      ps += __shfl_xor(ps, 2, 64);
      ps += __shfl_xor(ps, 4, 64);
      ps += __shfl_xor(ps, 8, 64);
      l[r] = l[r] * sc[r] + ps;
      pw[(blk * 4 + r) * 32 + jc] = (_Float16)pA;
      pw[(blk * 4 + r) * 32 + 16 + jc] = (_Float16)pB;
    }
    #pragma unroll
    for (int dt = 0; dt < 4; ++dt)
      #pragma unroll
      for (int r = 0; r < 4; ++r)
        o[dt][r] *= sc[r];
    f16x8 pf = *(const f16x8*)&pw[jc * 32 + blk * 8];
    #pragma unroll
    for (int dt = 0; dt < 4; ++dt)
      o[dt] = __builtin_amdgcn_mfma_f32_16x16x32_f16(pf, v0[dt], o[dt], 0, 0, 0);
  }

  // =========== jt = 1 ===========
  aA = f32x4{0.f, 0.f, 0.f, 0.f};
  aA = __builtin_amdgcn_mfma_f32_16x16x32_f16(qa0, k1A0, aA, 0, 0, 0);
  aA = __builtin_amdgcn_mfma_f32_16x16x32_f16(qa1, k1A1, aA, 0, 0, 0);
  aB = f32x4{0.f, 0.f, 0.f, 0.f};
  aB = __builtin_amdgcn_mfma_f32_16x16x32_f16(qa0, k1B0, aB, 0, 0, 0);
  aB = __builtin_amdgcn_mfma_f32_16x16x32_f16(qa1, k1B1, aB, 0, 0, 0);
  {
    float sA[4], sB[4], sc[4];
    #pragma unroll
    for (int r = 0; r < 4; ++r) {
      const int br = (blk * 4 + r) * 520;
      sA[r] = aA[r] + (float)bst[br + j01 + jc];
      sB[r] = aB[r] + (float)bst[br + j01 + 16 + jc];
    }
    #pragma unroll
    for (int r = 0; r < 4; ++r) {
      float mx = fmaxf(sA[r], sB[r]);
      mx = fmaxf(mx, __shfl_xor(mx, 1, 64));
      mx = fmaxf(mx, __shfl_xor(mx, 2, 64));
      mx = fmaxf(mx, __shfl_xor(mx, 4, 64));
      mx = fmaxf(mx, __shfl_xor(mx, 8, 64));
      float mn = fmaxf(m[r], mx);
      sc[r] = __expf(m[r] - mn);
      m[r] = mn;
      float pA = __expf(sA[r] - mn);
      float pB = __expf(sB[r] - mn);
      float ps = pA + pB;
      ps += __shfl_xor(ps, 1, 64);
      ps += __shfl_xor(ps, 2, 64);
      ps += __shfl_xor(ps, 4, 64);
      ps += __shfl_xor(ps, 8, 64);
      l[r] = l[r] * sc[r] + ps;
      pw[(blk * 4 + r) * 32 + jc] = (_Float16)pA;
      pw[(blk * 4 + r) * 32 + 16 + jc] = (_Float16)pB;
    }
    #pragma unroll
    for (int dt = 0; dt < 4; ++dt)
      #pragma unroll
      for (int r = 0; r < 4; ++r)
        o[dt][r] *= sc[r];
    f16x8 pf = *(const f16x8*)&pw[jc * 32 + blk * 8];
    #pragma unroll
    for (int dt = 0; dt < 4; ++dt)
      o[dt] = __builtin_amdgcn_mfma_f32_16x16x32_f16(pf, v1[dt], o[dt], 0, 0, 0);
  }

  __syncthreads();   // all waves done with bst before olds overwrite
  #pragma unroll
  for (int dt = 0; dt < 4; ++dt)
    #pragma unroll
    for (int r = 0; r < 4; ++r)
      olds[(w * 16 + blk * 4 + r) * 65 + dt * 16 + jc] = o[dt][r];
  if (jc == 0) {
    #pragma unroll
    for (int r = 0; r < 4; ++r) {
      mls[(w * 16 + blk * 4 + r) * 2 + 0] = m[r];
      mls[(w * 16 + blk * 4 + r) * 2 + 1] = l[r];
    }
  }
  __syncthreads();
  #pragma unroll
  for (int itx = 0; itx < 2; ++itx) {
    int idx = tid + itx * 512;
    int q = idx >> 6, d = idx & 63;
    float M = -1e30f;
    #pragma unroll
    for (int ww = 0; ww < 8; ++ww) M = fmaxf(M, mls[(ww * 16 + q) * 2]);
    float L = 0.f, acc = 0.f;
    #pragma unroll
    for (int ww = 0; ww < 8; ++ww) {
      float e = __expf(mls[(ww * 16 + q) * 2] - M);
      L += mls[(ww * 16 + q) * 2 + 1] * e;
      acc += olds[(ww * 16 + q) * 65 + d] * e;
    }
    ao16[(b * 512 + i0 + q) * 512 + h * 64 + d] = (_Float16)(acc / L);
  }
}

// ---------------- K4: output GEMM via MFMA, 2-deep prefetch -----------------
__global__ __launch_bounds__(256) void k_out(
    const _Float16* __restrict__ ao16, const _Float16* __restrict__ Wot,
    const float* __restrict__ bout, float* __restrict__ out) {
  __shared__ __align__(16) unsigned short SM[6144];    // 12 KB
  _Float16* Ah = (_Float16*)SM;            // [32][64] 4 KB
  _Float16* Bh = (_Float16*)SM + 2048;     // [64][64] 8 KB

  // XCD swizzle: 4 mt-groups per XCD
  const int lb = (blockIdx.x & 7) * 32 + (blockIdx.x >> 3);
  const int mt = lb >> 3, nt = lb & 7;
  const int m0 = mt * 32, n0 = nt * 64;
  const int t = threadIdx.x;
  const int w = t >> 6, lane = t & 63, blk = lane >> 4, jc = lane & 15;
  const int mh_ = (w & 1) * 16, nh_ = (w >> 1) * 32;
  const int sm = t >> 3, sq = t & 7;     // sm: 0..31

  f32x4 acc[2];
  acc[0] = f32x4{0.f, 0.f, 0.f, 0.f};
  acc[1] = f32x4{0.f, 0.f, 0.f, 0.f};

  f16x8 pa[2], pb[2][2];
  #pragma unroll
  for (int s = 0; s < 2; ++s) {
    pa[s] = *(const f16x8*)&ao16[(m0 + sm) * 512 + s * 64 + sq * 8];
    #pragma unroll
    for (int c = 0; c < 2; ++c)
      pb[s][c] = *(const f16x8*)&Wot[(n0 + sm + c * 32) * 512 + s * 64 + sq * 8];
  }
  for (int it = 0; it < 8; ++it) {
    const int slot = it & 1;
    *(f16x8*)&Ah[swq(sm, sq)] = pa[slot];
    #pragma unroll
    for (int c = 0; c < 2; ++c)
      *(f16x8*)&Bh[swq(sm + c * 32, sq)] = pb[slot][c];
    __syncthreads();
    if (it < 6) {
      int k0 = (it + 2) * 64;
      pa[slot] = *(const f16x8*)&ao16[(m0 + sm) * 512 + k0 + sq * 8];
      #pragma unroll
      for (int c = 0; c < 2; ++c)
        pb[slot][c] = *(const f16x8*)&Wot[(n0 + sm + c * 32) * 512 + k0 + sq * 8];
    }
    #pragma unroll
    for (int h = 0; h < 2; ++h) {
      int q = h * 4 + blk;
      f16x8 a0 = *(const f16x8*)&Ah[swq(mh_ + jc, q)];
      f16x8 b0 = *(const f16x8*)&Bh[swq(nh_ + jc, q)];
      f16x8 b1 = *(const f16x8*)&Bh[swq(nh_ + 16 + jc, q)];
      acc[0] = __builtin_amdgcn_mfma_f32_16x16x32_f16(a0, b0, acc[0], 0, 0, 0);
      acc[1] = __builtin_amdgcn_mfma_f32_16x16x32_f16(a0, b1, acc[1], 0, 0, 0);
    }
    __syncthreads();
  }
  #pragma unroll
  for (int j = 0; j < 2; ++j) {
    int n = n0 + nh_ + j * 16 + jc;
    float bb = bout[n];
    #pragma unroll
    for (int r = 0; r < 4; ++r) {
      int row = m0 + mh_ + blk * 4 + r;
      out[row * 512 + n] = acc[j][r] + bb;
    }
  }
}

extern "C" void kernel_launch(void* const* d_in, const int* in_sizes, int n_in,
                              void* d_out, int out_size, void* d_ws, size_t ws_size,
                              hipStream_t stream) {
  const float* x    = (const float*)d_in[0];
  const float* pos  = (const float*)d_in[1];
  const float* Wqkv = (const float*)d_in[2];
  const float* Wout = (const float*)d_in[3];
  const float* bout = (const float*)d_in[4];
  const float* W1   = (const float*)d_in[5];
  const float* b1   = (const float*)d_in[6];
  const float* W2   = (const float*)d_in[7];
  const float* b2   = (const float*)d_in[8];
  float* out = (float*)d_out;
  char* base = (char*)d_ws;

  __half* Tx       = (__half*)(base);                       // 16 KB
  __half* Ty       = (__half*)(base + 16384);               // 16 KB
  _Float16* Wt     = (_Float16*)(base + 32768);             // 1.5 MB
  _Float16* Wot    = (_Float16*)(base + 1605632);           // 512 KB
  _Float16* q16    = (_Float16*)(base + 2129920);           // 1 MB
  _Float16* k16    = (_Float16*)(base + 3178496);           // 1 MB
  _Float16* vt16   = (_Float16*)(base + 4227072);           // 1 MB
  _Float16* bias16 = (_Float16*)(base + 5275648);           // 8 MB
  _Float16* ao16   = (_Float16*)(base + 13664256);          // 1 MB

  hipLaunchKernelGGL(k_prep, dim3(1088), dim3(256), 0, stream,
                     Wqkv, Wout, W1, b1, Wt, Wot, Tx, Ty);
  hipLaunchKernelGGL(k_fused, dim3(1216), dim3(512), 0, stream,
                     x, Wt, q16, k16, vt16, pos, Tx, Ty, W2, b2, bias16);
  hipLaunchKernelGGL(k_attn, dim3(512), dim3(512), 0, stream,
                     q16, k16, vt16, bias16, ao16);
  hipLaunchKernelGGL(k_out, dim3(256), dim3(256), 0, stream,
                     ao16, Wot, bout, out);
}